// Round 8
// baseline (257.037 us; speedup 1.0000x reference)
//
#include <hip/hip_runtime.h>
#include <cstddef>
#include <cstdint>

// B=2, L=2048, H=16, HD=64, C=1024. All matmuls on bf16 MFMA, f32 accum.

typedef __attribute__((ext_vector_type(8))) short short8;
typedef __attribute__((ext_vector_type(4))) float f32x4;
typedef __attribute__((ext_vector_type(4))) unsigned short ushort4_t;
typedef __attribute__((ext_vector_type(2))) unsigned int uint2_t;

__device__ __forceinline__ unsigned short f2bf(float f) {
  union { float f; unsigned int u; } c{f};
  unsigned int u = c.u;
  u += 0x7fff + ((u >> 16) & 1);   // round-to-nearest-even
  return (unsigned short)(u >> 16);
}
__device__ __forceinline__ float bf2f(unsigned short h) {
  union { unsigned int u; float f; } c{((unsigned int)h) << 16};
  return c.f;
}
// pack two f32 -> [bf16(a) | bf16(b)<<16] by truncation, single v_perm_b32.
__device__ __forceinline__ unsigned int pack_bf16_trunc(float a, float b) {
  union { float f; unsigned int u; } ca{a}, cb{b};
  return __builtin_amdgcn_perm(cb.u, ca.u, 0x07060302u);
}

// ---------------------------------------------------------------------------
// f32 -> bf16 elementwise convert (vectorized)
// ---------------------------------------------------------------------------
__global__ __launch_bounds__(256) void cvt_f32_bf16(const float* __restrict__ src,
                                                    unsigned short* __restrict__ dst,
                                                    int n4) {
  int i = blockIdx.x * 256 + threadIdx.x;
  int stride = gridDim.x * 256;
  for (; i < n4; i += stride) {
    float4 v = reinterpret_cast<const float4*>(src)[i];
    ushort4_t o;
    o.x = f2bf(v.x); o.y = f2bf(v.y); o.z = f2bf(v.z); o.w = f2bf(v.w);
    reinterpret_cast<ushort4_t*>(dst)[i] = o;
  }
}

// ---------------------------------------------------------------------------
// W[K][N] f32  ->  WT[N][K] bf16   (64x64 tiles via LDS)
// ---------------------------------------------------------------------------
__global__ __launch_bounds__(256) void transpose_cvt(const float* __restrict__ W,
                                                     unsigned short* __restrict__ WT,
                                                     int K, int N) {
  __shared__ float T[64][65];
  const int n0 = blockIdx.x * 64, k0 = blockIdx.y * 64;
  const int t = threadIdx.x;
  const int r = t >> 4, c4 = (t & 15) * 4;
#pragma unroll
  for (int rr = 0; rr < 4; ++rr) {
    int kk = rr * 16 + r;
    float4 v = *reinterpret_cast<const float4*>(W + (size_t)(k0 + kk) * N + n0 + c4);
    T[kk][c4 + 0] = v.x; T[kk][c4 + 1] = v.y; T[kk][c4 + 2] = v.z; T[kk][c4 + 3] = v.w;
  }
  __syncthreads();
#pragma unroll
  for (int rr = 0; rr < 4; ++rr) {
    int nn = rr * 16 + r;
    ushort4_t o;
    o.x = f2bf(T[c4 + 0][nn]); o.y = f2bf(T[c4 + 1][nn]);
    o.z = f2bf(T[c4 + 2][nn]); o.w = f2bf(T[c4 + 3][nn]);
    *reinterpret_cast<ushort4_t*>(WT + (size_t)(n0 + nn) * K + k0 + c4) = o;
  }
}

// ---------------------------------------------------------------------------
// 128x128x(BK=32) bf16 MFMA GEMM, K=1024, reg-prefetch, XCD-swizzled 1-D grid
// (8 XCDs x NPX n-tiles x 32 m-tiles).
// EPI 0: fused {bias + RoPE(q,k) + V-transpose} epilogue
//        (q scaled by 0.125*log2(e) for log2-domain softmax).
// EPI 1: f32 out + bias.
// ---------------------------------------------------------------------------
template <int EPI, int NPX>
__global__ __launch_bounds__(256) void mm128p(const unsigned short* __restrict__ A,
                                              const unsigned short* __restrict__ Bt,
                                              const float* __restrict__ bias,
                                              unsigned short* __restrict__ q,
                                              unsigned short* __restrict__ k,
                                              unsigned short* __restrict__ v,
                                              float* __restrict__ outf,
                                              const float* __restrict__ freqs) {
  __shared__ unsigned short As[128][40];
  __shared__ unsigned short Bs[128][40];
  // XCD swizzle: bid%8 -> XCD; per XCD: NPX n-tiles, inner sweep over 32 m-tiles
  const int bid = blockIdx.x;
  const int xcd = bid & 7, c = bid >> 3;
  const int m0 = (c & 31) * 128;
  const int n0 = (xcd * NPX + (c >> 5)) * 128;
  const int t = threadIdx.x, l = t & 63, w = t >> 6;
  const int wm = w >> 1, wn = w & 1;
  const int lr = l & 15, lg = l >> 4;
  const int lrow = t >> 1, lk = (t & 1) * 16;

  const unsigned short* ap = A + (size_t)(m0 + lrow) * 1024 + lk;
  const unsigned short* bp = Bt + (size_t)(n0 + lrow) * 1024 + lk;

  short8 av0 = *reinterpret_cast<const short8*>(ap);
  short8 av1 = *reinterpret_cast<const short8*>(ap + 8);
  short8 bv0 = *reinterpret_cast<const short8*>(bp);
  short8 bv1 = *reinterpret_cast<const short8*>(bp + 8);

  f32x4 acc[4][4] = {};
#pragma unroll 2
  for (int k0 = 0; k0 < 1024; k0 += 32) {
    __syncthreads();
    *reinterpret_cast<short8*>(&As[lrow][lk]) = av0;
    *reinterpret_cast<short8*>(&As[lrow][lk + 8]) = av1;
    *reinterpret_cast<short8*>(&Bs[lrow][lk]) = bv0;
    *reinterpret_cast<short8*>(&Bs[lrow][lk + 8]) = bv1;
    __syncthreads();
    const int kn = (k0 + 32) & 1023;
    short8 an0 = *reinterpret_cast<const short8*>(ap + kn);
    short8 an1 = *reinterpret_cast<const short8*>(ap + kn + 8);
    short8 bn0 = *reinterpret_cast<const short8*>(bp + kn);
    short8 bn1 = *reinterpret_cast<const short8*>(bp + kn + 8);
    short8 af[4], bf[4];
#pragma unroll
    for (int i = 0; i < 4; ++i)
      af[i] = *reinterpret_cast<const short8*>(&As[wm * 64 + i * 16 + lr][lg * 8]);
#pragma unroll
    for (int j = 0; j < 4; ++j)
      bf[j] = *reinterpret_cast<const short8*>(&Bs[wn * 64 + j * 16 + lr][lg * 8]);
#pragma unroll
    for (int i = 0; i < 4; ++i)
#pragma unroll
      for (int j = 0; j < 4; ++j)
        acc[i][j] = __builtin_amdgcn_mfma_f32_16x16x32_bf16(af[i], bf[j], acc[i][j], 0, 0, 0);
    av0 = an0; av1 = an1; bv0 = bn0; bv1 = bn1;
  }

  if constexpr (EPI == 0) {
    // n-range of this (block, wn): [nbase, nbase+64) -> one s (q/k/v), one head h.
    // thread's 4 j-columns are d = {lr, 16+lr, 32+lr, 48+lr}: rotation pairs
    // (j0,j2) with f=lr and (j1,j3) with f=16+lr.
    const int nbase = n0 + wn * 64;
    const int s = nbase >> 10;
    const int h = (nbase >> 6) & 15;
    const float b0 = bias[nbase + lr],      b1 = bias[nbase + 16 + lr];
    const float b2 = bias[nbase + 32 + lr], b3 = bias[nbase + 48 + lr];
    if (s < 2) {
      unsigned short* dst = (s == 0) ? q : k;
      const float scale = (s == 0) ? 0.18033688011112042f : 1.0f;  // 0.125*log2(e)
      const float f0 = freqs[h * 32 + lr];
      const float f1 = freqs[h * 32 + 16 + lr];
#pragma unroll
      for (int i = 0; i < 4; ++i)
#pragma unroll
        for (int r = 0; r < 4; ++r) {
          const int m = m0 + wm * 64 + i * 16 + lg * 4 + r;
          const int bb = m >> 11, lseq = m & 2047;
          float sn0, cs0, sn1, cs1;
          sincosf((float)lseq * f0, &sn0, &cs0);
          sincosf((float)lseq * f1, &sn1, &cs1);
          const float t0 = acc[i][0][r] + b0;
          const float t1 = acc[i][1][r] + b1;
          const float t2 = acc[i][2][r] + b2;
          const float t3 = acc[i][3][r] + b3;
          unsigned short* p = dst + (size_t)(((bb << 4) + h) * 2048 + lseq) * 64;
          p[lr]      = f2bf((t0 * cs0 - t2 * sn0) * scale);
          p[lr + 32] = f2bf((t0 * sn0 + t2 * cs0) * scale);
          p[lr + 16] = f2bf((t1 * cs1 - t3 * sn1) * scale);
          p[lr + 48] = f2bf((t1 * sn1 + t3 * cs1) * scale);
        }
    } else {
      // v: write transposed Vt[bh][d][lseq] (4 lseq-contiguous bf16 per store)
      const float bj[4] = {b0, b1, b2, b3};
#pragma unroll
      for (int j = 0; j < 4; ++j) {
        const int d = j * 16 + lr;
#pragma unroll
        for (int i = 0; i < 4; ++i) {
          const int m = m0 + wm * 64 + i * 16 + lg * 4;
          const int bb = m >> 11, lseq0 = m & 2047;
          ushort4_t o;
#pragma unroll
          for (int r = 0; r < 4; ++r) o[r] = f2bf(acc[i][j][r] + bj[j]);
          *reinterpret_cast<ushort4_t*>(
              v + ((size_t)(((bb << 4) + h) * 64 + d)) * 2048 + lseq0) = o;
        }
      }
    }
  } else {
#pragma unroll
    for (int j = 0; j < 4; ++j) {
      const int n = n0 + wn * 64 + j * 16 + lr;
      const float bb = bias[n];
#pragma unroll
      for (int i = 0; i < 4; ++i)
#pragma unroll
        for (int r = 0; r < 4; ++r) {
          const int m = m0 + wm * 64 + i * 16 + lg * 4 + r;
          outf[(size_t)m * 1024 + n] = acc[i][j][r] + bb;
        }
    }
  }
}

// ---------------------------------------------------------------------------
// Flash attention v5 + XCD swizzle: fat waves (QBLK=64/wave, 4 waves, 256
// q-rows/block), K/V double-buffered XOR-swizzled LDS, swapped QK^T,
// in-register log2 softmax, PV from LDS V-frags, P via wave-private LDS.
// Swizzle: 4 bh per XCD x 8 q-tiles -> each bh's K/V lives in ONE L2.
// ---------------------------------------------------------------------------
__global__ __launch_bounds__(256, 2) void attn_mfma5(const unsigned short* __restrict__ Q,
                                                     const unsigned short* __restrict__ K,
                                                     const unsigned short* __restrict__ Vt,
                                                     unsigned short* __restrict__ O) {
  __shared__ unsigned short Ks[2][64 * 64];
  __shared__ unsigned short Vs[2][64 * 64];
  __shared__ unsigned short Pb[4][4][16][72];
  const int bid = blockIdx.x;
  const int xcd = bid & 7, c = bid >> 3;
  const int bh = (xcd << 2) + (c >> 3);
  const int q0 = (c & 7) * 256;
  const int t = threadIdx.x, l = t & 63, w = t >> 6;
  const int lr = l & 15, lg = l >> 4;
  const unsigned short* Qb = Q + (size_t)bh * (2048 * 64);
  const unsigned short* Kb = K + (size_t)bh * (2048 * 64);
  const unsigned short* Vb = Vt + (size_t)bh * (64 * 2048);
  const int qrow = q0 + w * 64;

  const int srow = w * 16 + (l >> 3);
  const int xo   = ((l & 7) ^ (srow & 7)) * 8;
  const int swzA = srow * 64 + xo;
  const int swzB = (srow + 8) * 64 + xo;
  const unsigned short* kgp = Kb + (size_t)srow * 64 + (l & 7) * 8;
  const unsigned short* vgp = Vb + (size_t)srow * 2048 + (l & 7) * 8;

  short8 qf[4][2];
#pragma unroll
  for (int g = 0; g < 4; ++g)
#pragma unroll
    for (int h = 0; h < 2; ++h)
      qf[g][h] = *reinterpret_cast<const short8*>(Qb + (size_t)(qrow + g * 16 + lr) * 64 + h * 32 + lg * 8);

  f32x4 oacc[4][4] = {};
  float m_run[4] = {-3.0e38f, -3.0e38f, -3.0e38f, -3.0e38f};
  float l_run[4] = {0.0f, 0.0f, 0.0f, 0.0f};

  {
    short8 k0a = *reinterpret_cast<const short8*>(kgp);
    short8 k0b = *reinterpret_cast<const short8*>(kgp + 8 * 64);
    short8 v0a = *reinterpret_cast<const short8*>(vgp);
    short8 v0b = *reinterpret_cast<const short8*>(vgp + 8 * 2048);
    *reinterpret_cast<short8*>(&Ks[0][swzA]) = k0a;
    *reinterpret_cast<short8*>(&Ks[0][swzB]) = k0b;
    *reinterpret_cast<short8*>(&Vs[0][swzA]) = v0a;
    *reinterpret_cast<short8*>(&Vs[0][swzB]) = v0b;
  }

  for (int it = 0; it < 32; ++it) {
    const int cur = it & 1;
    __syncthreads();

    short8 kna, knb, vna, vnb;
    if (it < 31) {
      kna = *reinterpret_cast<const short8*>(kgp + (size_t)(it + 1) * 4096);
      knb = *reinterpret_cast<const short8*>(kgp + (size_t)(it + 1) * 4096 + 8 * 64);
      vna = *reinterpret_cast<const short8*>(vgp + (it + 1) * 64);
      vnb = *reinterpret_cast<const short8*>(vgp + (it + 1) * 64 + 8 * 2048);
    }

    short8 kfa[4][2];
#pragma unroll
    for (int n = 0; n < 4; ++n)
#pragma unroll
      for (int h = 0; h < 2; ++h)
        kfa[n][h] = *reinterpret_cast<const short8*>(
            &Ks[cur][(n * 16 + lr) * 64 + (((h * 4 + lg) ^ (lr & 7)) * 8)]);

#pragma unroll
    for (int g = 0; g < 4; ++g) {
      f32x4 sacc[4] = {};
      __builtin_amdgcn_s_setprio(1);
#pragma unroll
      for (int n = 0; n < 4; ++n) {
        sacc[n] = __builtin_amdgcn_mfma_f32_16x16x32_bf16(kfa[n][0], qf[g][0], sacc[n], 0, 0, 0);
        sacc[n] = __builtin_amdgcn_mfma_f32_16x16x32_bf16(kfa[n][1], qf[g][1], sacc[n], 0, 0, 0);
      }
      __builtin_amdgcn_s_setprio(0);
      float m0 = fmaxf(fmaxf(sacc[0][0], sacc[0][1]), fmaxf(sacc[0][2], sacc[0][3]));
      float m1 = fmaxf(fmaxf(sacc[1][0], sacc[1][1]), fmaxf(sacc[1][2], sacc[1][3]));
      float m2 = fmaxf(fmaxf(sacc[2][0], sacc[2][1]), fmaxf(sacc[2][2], sacc[2][3]));
      float m3 = fmaxf(fmaxf(sacc[3][0], sacc[3][1]), fmaxf(sacc[3][2], sacc[3][3]));
      float mx = fmaxf(fmaxf(m0, m1), fmaxf(m2, m3));
      mx = fmaxf(mx, __shfl_xor(mx, 16));
      mx = fmaxf(mx, __shfl_xor(mx, 32));
      if (__any(mx > m_run[g] + 8.0f)) {
        const float m_new = fmaxf(m_run[g], mx);
        const float alpha = __builtin_amdgcn_exp2f(m_run[g] - m_new);
        m_run[g] = m_new;
        l_run[g] *= alpha;
#pragma unroll
        for (int sub = 0; sub < 4; ++sub)
#pragma unroll
          for (int r = 0; r < 4; ++r) oacc[g][sub][r] *= alpha;
      }
      const float mq = m_run[g];
      float p[16];
#pragma unroll
      for (int n = 0; n < 4; ++n)
#pragma unroll
        for (int r = 0; r < 4; ++r)
          p[n * 4 + r] = __builtin_amdgcn_exp2f(sacc[n][r] - mq);
      float ssum = ((p[0] + p[1]) + (p[2] + p[3])) + ((p[4] + p[5]) + (p[6] + p[7]));
      ssum += ((p[8] + p[9]) + (p[10] + p[11])) + ((p[12] + p[13]) + (p[14] + p[15]));
      ssum += __shfl_xor(ssum, 16);
      ssum += __shfl_xor(ssum, 32);
      l_run[g] += ssum;
#pragma unroll
      for (int n = 0; n < 4; ++n) {
        uint2_t pk;
        pk.x = pack_bf16_trunc(p[n * 4 + 0], p[n * 4 + 1]);
        pk.y = pack_bf16_trunc(p[n * 4 + 2], p[n * 4 + 3]);
        *reinterpret_cast<uint2_t*>(&Pb[w][g][lr][n * 16 + lg * 4]) = pk;
      }
    }

    short8 vfa[4][2];
#pragma unroll
    for (int sub = 0; sub < 4; ++sub)
#pragma unroll
      for (int kb = 0; kb < 2; ++kb)
        vfa[sub][kb] = *reinterpret_cast<const short8*>(
            &Vs[cur][(sub * 16 + lr) * 64 + (((kb * 4 + lg) ^ (lr & 7)) * 8)]);

#pragma unroll
    for (int g = 0; g < 4; ++g) {
      short8 pb[2];
#pragma unroll
      for (int kb = 0; kb < 2; ++kb)
        pb[kb] = *reinterpret_cast<const short8*>(&Pb[w][g][lr][kb * 32 + lg * 8]);
      __builtin_amdgcn_s_setprio(1);
#pragma unroll
      for (int sub = 0; sub < 4; ++sub) {
        oacc[g][sub] = __builtin_amdgcn_mfma_f32_16x16x32_bf16(vfa[sub][0], pb[0], oacc[g][sub], 0, 0, 0);
        oacc[g][sub] = __builtin_amdgcn_mfma_f32_16x16x32_bf16(vfa[sub][1], pb[1], oacc[g][sub], 0, 0, 0);
      }
      __builtin_amdgcn_s_setprio(0);
    }

    __syncthreads();
    if (it < 31) {
      const int nxt = cur ^ 1;
      *reinterpret_cast<short8*>(&Ks[nxt][swzA]) = kna;
      *reinterpret_cast<short8*>(&Ks[nxt][swzB]) = knb;
      *reinterpret_cast<short8*>(&Vs[nxt][swzA]) = vna;
      *reinterpret_cast<short8*>(&Vs[nxt][swzB]) = vnb;
    }
  }

  const int b = bh >> 4, h = bh & 15;
#pragma unroll
  for (int g = 0; g < 4; ++g) {
    const float inv = 1.0f / l_run[g];
    unsigned short* Ob = O + ((size_t)(b * 2048 + qrow + g * 16 + lr)) * 1024 + h * 64;
#pragma unroll
    for (int sub = 0; sub < 4; ++sub) {
      ushort4_t o;
#pragma unroll
      for (int r = 0; r < 4; ++r) o[r] = f2bf(oacc[g][sub][r] * inv);
      *reinterpret_cast<ushort4_t*>(Ob + sub * 16 + lg * 4) = o;
    }
  }
}

// ---------------------------------------------------------------------------
extern "C" void kernel_launch(void* const* d_in, const int* in_sizes, int n_in,
                              void* d_out, int out_size, void* d_ws, size_t ws_size,
                              hipStream_t stream) {
  const float* x          = (const float*)d_in[0];
  const float* w_qkv      = (const float*)d_in[1];
  const float* b_qkv      = (const float*)d_in[2];
  const float* w_out      = (const float*)d_in[3];
  const float* b_out      = (const float*)d_in[4];
  const float* rope_freqs = (const float*)d_in[5];
  float* out = (float*)d_out;

  char* ws = (char*)d_ws;
  unsigned short* x_bf    = (unsigned short*)(ws + 0);          // 8 MB (aliased by attn_bf)
  unsigned short* attn_bf = x_bf;
  unsigned short* q_bf    = (unsigned short*)(ws + 8388608);
  unsigned short* k_bf    = (unsigned short*)(ws + 16777216);
  unsigned short* v_t     = (unsigned short*)(ws + 33554432);   // [bh][d][l] bf16, 8 MB
  unsigned short* wqkvT   = (unsigned short*)(ws + 41943040);
  unsigned short* woutT   = (unsigned short*)(ws + 48234496);

  hipLaunchKernelGGL(cvt_f32_bf16, dim3(1024), dim3(256), 0, stream, x, x_bf, 1048576);
  hipLaunchKernelGGL(transpose_cvt, dim3(48, 16), dim3(256), 0, stream, w_qkv, wqkvT, 1024, 3072);
  hipLaunchKernelGGL(transpose_cvt, dim3(16, 16), dim3(256), 0, stream, w_out, woutT, 1024, 1024);
  // qkv GEMM + fused bias/RoPE/V-transpose epilogue (768 blocks, XCD-swizzled)
  hipLaunchKernelGGL((mm128p<0, 3>), dim3(768), dim3(256), 0, stream,
                     x_bf, wqkvT, b_qkv, q_bf, k_bf, v_t, (float*)nullptr, rope_freqs);
  // attention (256 blocks, XCD-swizzled)
  hipLaunchKernelGGL(attn_mfma5, dim3(256), dim3(256), 0, stream, q_bf, k_bf, v_t, attn_bf);
  // out projection (256 blocks, XCD-swizzled)
  hipLaunchKernelGGL((mm128p<1, 1>), dim3(256), dim3(256), 0, stream,
                     attn_bf, woutT, b_out,
                     (unsigned short*)nullptr, (unsigned short*)nullptr, (unsigned short*)nullptr,
                     out, (const float*)nullptr);
}

// Round 9
// 233.811 us; speedup vs baseline: 1.0993x; 1.0993x over previous
//
#include <hip/hip_runtime.h>
#include <cstddef>
#include <cstdint>

// B=2, L=2048, H=16, HD=64, C=1024. All matmuls on bf16 MFMA, f32 accum.

typedef __attribute__((ext_vector_type(8))) short short8;
typedef __attribute__((ext_vector_type(4))) float f32x4;
typedef __attribute__((ext_vector_type(4))) unsigned short ushort4_t;
typedef __attribute__((ext_vector_type(2))) unsigned int uint2_t;

__device__ __forceinline__ unsigned short f2bf(float f) {
  union { float f; unsigned int u; } c{f};
  unsigned int u = c.u;
  u += 0x7fff + ((u >> 16) & 1);   // round-to-nearest-even
  return (unsigned short)(u >> 16);
}
__device__ __forceinline__ float bf2f(unsigned short h) {
  union { unsigned int u; float f; } c{((unsigned int)h) << 16};
  return c.f;
}
// pack two f32 -> [bf16(a) | bf16(b)<<16] by truncation, single v_perm_b32.
__device__ __forceinline__ unsigned int pack_bf16_trunc(float a, float b) {
  union { float f; unsigned int u; } ca{a}, cb{b};
  return __builtin_amdgcn_perm(cb.u, ca.u, 0x07060302u);
}

// ---------------------------------------------------------------------------
// f32 -> bf16 elementwise convert (vectorized)
// ---------------------------------------------------------------------------
__global__ __launch_bounds__(256) void cvt_f32_bf16(const float* __restrict__ src,
                                                    unsigned short* __restrict__ dst,
                                                    int n4) {
  int i = blockIdx.x * 256 + threadIdx.x;
  int stride = gridDim.x * 256;
  for (; i < n4; i += stride) {
    float4 v = reinterpret_cast<const float4*>(src)[i];
    ushort4_t o;
    o.x = f2bf(v.x); o.y = f2bf(v.y); o.z = f2bf(v.z); o.w = f2bf(v.w);
    reinterpret_cast<ushort4_t*>(dst)[i] = o;
  }
}

// ---------------------------------------------------------------------------
// W[K][N] f32  ->  WT[N][K] bf16   (64x64 tiles via LDS)
// ---------------------------------------------------------------------------
__global__ __launch_bounds__(256) void transpose_cvt(const float* __restrict__ W,
                                                     unsigned short* __restrict__ WT,
                                                     int K, int N) {
  __shared__ float T[64][65];
  const int n0 = blockIdx.x * 64, k0 = blockIdx.y * 64;
  const int t = threadIdx.x;
  const int r = t >> 4, c4 = (t & 15) * 4;
#pragma unroll
  for (int rr = 0; rr < 4; ++rr) {
    int kk = rr * 16 + r;
    float4 v = *reinterpret_cast<const float4*>(W + (size_t)(k0 + kk) * N + n0 + c4);
    T[kk][c4 + 0] = v.x; T[kk][c4 + 1] = v.y; T[kk][c4 + 2] = v.z; T[kk][c4 + 3] = v.w;
  }
  __syncthreads();
#pragma unroll
  for (int rr = 0; rr < 4; ++rr) {
    int nn = rr * 16 + r;
    ushort4_t o;
    o.x = f2bf(T[c4 + 0][nn]); o.y = f2bf(T[c4 + 1][nn]);
    o.z = f2bf(T[c4 + 2][nn]); o.w = f2bf(T[c4 + 3][nn]);
    *reinterpret_cast<ushort4_t*>(WT + (size_t)(n0 + nn) * K + k0 + c4) = o;
  }
}

// ---------------------------------------------------------------------------
// 128x128x(BK=64) bf16 MFMA GEMM, K=1024, reg-prefetch, XCD-swizzled 1-D grid
// (8 XCDs x NPX n-tiles x 32 m-tiles).  16 iterations, 32 MFMA each (halved
// barrier count vs BK=32).  LDS row stride 76 elems (152B): frag ds_read_b128
// hits 16 distinct banks across lr lanes.
// EPI 0: fused {bias + RoPE(q,k) + V-transpose} epilogue
//        (q scaled by 0.125*log2(e) for log2-domain softmax).
// EPI 1: f32 out + bias.
// ---------------------------------------------------------------------------
template <int EPI, int NPX>
__global__ __launch_bounds__(256, 2) void mm128b(const unsigned short* __restrict__ A,
                                                 const unsigned short* __restrict__ Bt,
                                                 const float* __restrict__ bias,
                                                 unsigned short* __restrict__ q,
                                                 unsigned short* __restrict__ k,
                                                 unsigned short* __restrict__ v,
                                                 float* __restrict__ outf,
                                                 const float* __restrict__ freqs) {
  __shared__ unsigned short As[128][76];
  __shared__ unsigned short Bs[128][76];
  const int bid = blockIdx.x;
  const int xcd = bid & 7, c = bid >> 3;
  const int m0 = (c & 31) * 128;
  const int n0 = (xcd * NPX + (c >> 5)) * 128;
  const int t = threadIdx.x, l = t & 63, w = t >> 6;
  const int wm = w >> 1, wn = w & 1;
  const int lr = l & 15, lg = l >> 4;
  const int lrow = t >> 1, lkc = (t & 1) * 32;   // 128 rows x 2 half-slabs of 32 elems

  const unsigned short* ap = A + (size_t)(m0 + lrow) * 1024 + lkc;
  const unsigned short* bp = Bt + (size_t)(n0 + lrow) * 1024 + lkc;

  // prologue: load K-slab 0
  short8 av[4], bv[4];
#pragma unroll
  for (int u = 0; u < 4; ++u) {
    av[u] = *reinterpret_cast<const short8*>(ap + u * 8);
    bv[u] = *reinterpret_cast<const short8*>(bp + u * 8);
  }

  f32x4 acc[4][4] = {};
#pragma unroll 2
  for (int k0 = 0; k0 < 1024; k0 += 64) {
    __syncthreads();
#pragma unroll
    for (int u = 0; u < 4; ++u) {
      *reinterpret_cast<short8*>(&As[lrow][lkc + u * 8]) = av[u];
      *reinterpret_cast<short8*>(&Bs[lrow][lkc + u * 8]) = bv[u];
    }
    __syncthreads();
    // prefetch next K-slab (wrap-masked: last iter reloads k=0, unused)
    const int kn = (k0 + 64) & 1023;
    short8 an[4], bn[4];
#pragma unroll
    for (int u = 0; u < 4; ++u) {
      an[u] = *reinterpret_cast<const short8*>(ap + kn + u * 8);
      bn[u] = *reinterpret_cast<const short8*>(bp + kn + u * 8);
    }
#pragma unroll
    for (int ks = 0; ks < 2; ++ks) {
      short8 af[4], bf[4];
#pragma unroll
      for (int i = 0; i < 4; ++i)
        af[i] = *reinterpret_cast<const short8*>(&As[wm * 64 + i * 16 + lr][ks * 32 + lg * 8]);
#pragma unroll
      for (int j = 0; j < 4; ++j)
        bf[j] = *reinterpret_cast<const short8*>(&Bs[wn * 64 + j * 16 + lr][ks * 32 + lg * 8]);
#pragma unroll
      for (int i = 0; i < 4; ++i)
#pragma unroll
        for (int j = 0; j < 4; ++j)
          acc[i][j] = __builtin_amdgcn_mfma_f32_16x16x32_bf16(af[i], bf[j], acc[i][j], 0, 0, 0);
    }
#pragma unroll
    for (int u = 0; u < 4; ++u) { av[u] = an[u]; bv[u] = bn[u]; }
  }

  if constexpr (EPI == 0) {
    // n-range of this (block, wn): [nbase, nbase+64) -> one s (q/k/v), one head h.
    // thread's 4 j-columns are d = {lr, 16+lr, 32+lr, 48+lr}: rotation pairs
    // (j0,j2) with f=lr and (j1,j3) with f=16+lr.
    const int nbase = n0 + wn * 64;
    const int s = nbase >> 10;
    const int h = (nbase >> 6) & 15;
    const float b0 = bias[nbase + lr],      b1 = bias[nbase + 16 + lr];
    const float b2 = bias[nbase + 32 + lr], b3 = bias[nbase + 48 + lr];
    if (s < 2) {
      unsigned short* dst = (s == 0) ? q : k;
      const float scale = (s == 0) ? 0.18033688011112042f : 1.0f;  // 0.125*log2(e)
      const float f0 = freqs[h * 32 + lr];
      const float f1 = freqs[h * 32 + 16 + lr];
#pragma unroll
      for (int i = 0; i < 4; ++i)
#pragma unroll
        for (int r = 0; r < 4; ++r) {
          const int m = m0 + wm * 64 + i * 16 + lg * 4 + r;
          const int bb = m >> 11, lseq = m & 2047;
          float sn0, cs0, sn1, cs1;
          sincosf((float)lseq * f0, &sn0, &cs0);
          sincosf((float)lseq * f1, &sn1, &cs1);
          const float t0 = acc[i][0][r] + b0;
          const float t1 = acc[i][1][r] + b1;
          const float t2 = acc[i][2][r] + b2;
          const float t3 = acc[i][3][r] + b3;
          unsigned short* p = dst + (size_t)(((bb << 4) + h) * 2048 + lseq) * 64;
          p[lr]      = f2bf((t0 * cs0 - t2 * sn0) * scale);
          p[lr + 32] = f2bf((t0 * sn0 + t2 * cs0) * scale);
          p[lr + 16] = f2bf((t1 * cs1 - t3 * sn1) * scale);
          p[lr + 48] = f2bf((t1 * sn1 + t3 * cs1) * scale);
        }
    } else {
      // v: write transposed Vt[bh][d][lseq] (4 lseq-contiguous bf16 per store)
      const float bj[4] = {b0, b1, b2, b3};
#pragma unroll
      for (int j = 0; j < 4; ++j) {
        const int d = j * 16 + lr;
#pragma unroll
        for (int i = 0; i < 4; ++i) {
          const int m = m0 + wm * 64 + i * 16 + lg * 4;
          const int bb = m >> 11, lseq0 = m & 2047;
          ushort4_t o;
#pragma unroll
          for (int r = 0; r < 4; ++r) o[r] = f2bf(acc[i][j][r] + bj[j]);
          *reinterpret_cast<ushort4_t*>(
              v + ((size_t)(((bb << 4) + h) * 64 + d)) * 2048 + lseq0) = o;
        }
      }
    }
  } else {
#pragma unroll
    for (int j = 0; j < 4; ++j) {
      const int n = n0 + wn * 64 + j * 16 + lr;
      const float bb = bias[n];
#pragma unroll
      for (int i = 0; i < 4; ++i)
#pragma unroll
        for (int r = 0; r < 4; ++r) {
          const int m = m0 + wm * 64 + i * 16 + lg * 4 + r;
          outf[(size_t)m * 1024 + n] = acc[i][j][r] + bb;
        }
    }
  }
}

// ---------------------------------------------------------------------------
// Flash attention v5 + XCD swizzle (UNCHANGED from round 8): fat waves
// (QBLK=64/wave, 4 waves, 256 q-rows/block), K/V double-buffered XOR-swizzled
// LDS, swapped QK^T, in-register log2 softmax, PV from LDS V-frags, P via
// wave-private LDS.  Swizzle: 4 bh per XCD x 8 q-tiles.
// ---------------------------------------------------------------------------
__global__ __launch_bounds__(256, 2) void attn_mfma5(const unsigned short* __restrict__ Q,
                                                     const unsigned short* __restrict__ K,
                                                     const unsigned short* __restrict__ Vt,
                                                     unsigned short* __restrict__ O) {
  __shared__ unsigned short Ks[2][64 * 64];
  __shared__ unsigned short Vs[2][64 * 64];
  __shared__ unsigned short Pb[4][4][16][72];
  const int bid = blockIdx.x;
  const int xcd = bid & 7, c = bid >> 3;
  const int bh = (xcd << 2) + (c >> 3);
  const int q0 = (c & 7) * 256;
  const int t = threadIdx.x, l = t & 63, w = t >> 6;
  const int lr = l & 15, lg = l >> 4;
  const unsigned short* Qb = Q + (size_t)bh * (2048 * 64);
  const unsigned short* Kb = K + (size_t)bh * (2048 * 64);
  const unsigned short* Vb = Vt + (size_t)bh * (64 * 2048);
  const int qrow = q0 + w * 64;

  const int srow = w * 16 + (l >> 3);
  const int xo   = ((l & 7) ^ (srow & 7)) * 8;
  const int swzA = srow * 64 + xo;
  const int swzB = (srow + 8) * 64 + xo;
  const unsigned short* kgp = Kb + (size_t)srow * 64 + (l & 7) * 8;
  const unsigned short* vgp = Vb + (size_t)srow * 2048 + (l & 7) * 8;

  short8 qf[4][2];
#pragma unroll
  for (int g = 0; g < 4; ++g)
#pragma unroll
    for (int h = 0; h < 2; ++h)
      qf[g][h] = *reinterpret_cast<const short8*>(Qb + (size_t)(qrow + g * 16 + lr) * 64 + h * 32 + lg * 8);

  f32x4 oacc[4][4] = {};
  float m_run[4] = {-3.0e38f, -3.0e38f, -3.0e38f, -3.0e38f};
  float l_run[4] = {0.0f, 0.0f, 0.0f, 0.0f};

  {
    short8 k0a = *reinterpret_cast<const short8*>(kgp);
    short8 k0b = *reinterpret_cast<const short8*>(kgp + 8 * 64);
    short8 v0a = *reinterpret_cast<const short8*>(vgp);
    short8 v0b = *reinterpret_cast<const short8*>(vgp + 8 * 2048);
    *reinterpret_cast<short8*>(&Ks[0][swzA]) = k0a;
    *reinterpret_cast<short8*>(&Ks[0][swzB]) = k0b;
    *reinterpret_cast<short8*>(&Vs[0][swzA]) = v0a;
    *reinterpret_cast<short8*>(&Vs[0][swzB]) = v0b;
  }

  for (int it = 0; it < 32; ++it) {
    const int cur = it & 1;
    __syncthreads();

    short8 kna, knb, vna, vnb;
    if (it < 31) {
      kna = *reinterpret_cast<const short8*>(kgp + (size_t)(it + 1) * 4096);
      knb = *reinterpret_cast<const short8*>(kgp + (size_t)(it + 1) * 4096 + 8 * 64);
      vna = *reinterpret_cast<const short8*>(vgp + (it + 1) * 64);
      vnb = *reinterpret_cast<const short8*>(vgp + (it + 1) * 64 + 8 * 2048);
    }

    short8 kfa[4][2];
#pragma unroll
    for (int n = 0; n < 4; ++n)
#pragma unroll
      for (int h = 0; h < 2; ++h)
        kfa[n][h] = *reinterpret_cast<const short8*>(
            &Ks[cur][(n * 16 + lr) * 64 + (((h * 4 + lg) ^ (lr & 7)) * 8)]);

#pragma unroll
    for (int g = 0; g < 4; ++g) {
      f32x4 sacc[4] = {};
      __builtin_amdgcn_s_setprio(1);
#pragma unroll
      for (int n = 0; n < 4; ++n) {
        sacc[n] = __builtin_amdgcn_mfma_f32_16x16x32_bf16(kfa[n][0], qf[g][0], sacc[n], 0, 0, 0);
        sacc[n] = __builtin_amdgcn_mfma_f32_16x16x32_bf16(kfa[n][1], qf[g][1], sacc[n], 0, 0, 0);
      }
      __builtin_amdgcn_s_setprio(0);
      float m0 = fmaxf(fmaxf(sacc[0][0], sacc[0][1]), fmaxf(sacc[0][2], sacc[0][3]));
      float m1 = fmaxf(fmaxf(sacc[1][0], sacc[1][1]), fmaxf(sacc[1][2], sacc[1][3]));
      float m2 = fmaxf(fmaxf(sacc[2][0], sacc[2][1]), fmaxf(sacc[2][2], sacc[2][3]));
      float m3 = fmaxf(fmaxf(sacc[3][0], sacc[3][1]), fmaxf(sacc[3][2], sacc[3][3]));
      float mx = fmaxf(fmaxf(m0, m1), fmaxf(m2, m3));
      mx = fmaxf(mx, __shfl_xor(mx, 16));
      mx = fmaxf(mx, __shfl_xor(mx, 32));
      if (__any(mx > m_run[g] + 8.0f)) {
        const float m_new = fmaxf(m_run[g], mx);
        const float alpha = __builtin_amdgcn_exp2f(m_run[g] - m_new);
        m_run[g] = m_new;
        l_run[g] *= alpha;
#pragma unroll
        for (int sub = 0; sub < 4; ++sub)
#pragma unroll
          for (int r = 0; r < 4; ++r) oacc[g][sub][r] *= alpha;
      }
      const float mq = m_run[g];
      float p[16];
#pragma unroll
      for (int n = 0; n < 4; ++n)
#pragma unroll
        for (int r = 0; r < 4; ++r)
          p[n * 4 + r] = __builtin_amdgcn_exp2f(sacc[n][r] - mq);
      float ssum = ((p[0] + p[1]) + (p[2] + p[3])) + ((p[4] + p[5]) + (p[6] + p[7]));
      ssum += ((p[8] + p[9]) + (p[10] + p[11])) + ((p[12] + p[13]) + (p[14] + p[15]));
      ssum += __shfl_xor(ssum, 16);
      ssum += __shfl_xor(ssum, 32);
      l_run[g] += ssum;
#pragma unroll
      for (int n = 0; n < 4; ++n) {
        uint2_t pk;
        pk.x = pack_bf16_trunc(p[n * 4 + 0], p[n * 4 + 1]);
        pk.y = pack_bf16_trunc(p[n * 4 + 2], p[n * 4 + 3]);
        *reinterpret_cast<uint2_t*>(&Pb[w][g][lr][n * 16 + lg * 4]) = pk;
      }
    }

    short8 vfa[4][2];
#pragma unroll
    for (int sub = 0; sub < 4; ++sub)
#pragma unroll
      for (int kb = 0; kb < 2; ++kb)
        vfa[sub][kb] = *reinterpret_cast<const short8*>(
            &Vs[cur][(sub * 16 + lr) * 64 + (((kb * 4 + lg) ^ (lr & 7)) * 8)]);

#pragma unroll
    for (int g = 0; g < 4; ++g) {
      short8 pb[2];
#pragma unroll
      for (int kb = 0; kb < 2; ++kb)
        pb[kb] = *reinterpret_cast<const short8*>(&Pb[w][g][lr][kb * 32 + lg * 8]);
      __builtin_amdgcn_s_setprio(1);
#pragma unroll
      for (int sub = 0; sub < 4; ++sub) {
        oacc[g][sub] = __builtin_amdgcn_mfma_f32_16x16x32_bf16(vfa[sub][0], pb[0], oacc[g][sub], 0, 0, 0);
        oacc[g][sub] = __builtin_amdgcn_mfma_f32_16x16x32_bf16(vfa[sub][1], pb[1], oacc[g][sub], 0, 0, 0);
      }
      __builtin_amdgcn_s_setprio(0);
    }

    __syncthreads();
    if (it < 31) {
      const int nxt = cur ^ 1;
      *reinterpret_cast<short8*>(&Ks[nxt][swzA]) = kna;
      *reinterpret_cast<short8*>(&Ks[nxt][swzB]) = knb;
      *reinterpret_cast<short8*>(&Vs[nxt][swzA]) = vna;
      *reinterpret_cast<short8*>(&Vs[nxt][swzB]) = vnb;
    }
  }

  const int b = bh >> 4, h = bh & 15;
#pragma unroll
  for (int g = 0; g < 4; ++g) {
    const float inv = 1.0f / l_run[g];
    unsigned short* Ob = O + ((size_t)(b * 2048 + qrow + g * 16 + lr)) * 1024 + h * 64;
#pragma unroll
    for (int sub = 0; sub < 4; ++sub) {
      ushort4_t o;
#pragma unroll
      for (int r = 0; r < 4; ++r) o[r] = f2bf(oacc[g][sub][r] * inv);
      *reinterpret_cast<ushort4_t*>(Ob + sub * 16 + lg * 4) = o;
    }
  }
}

// ---------------------------------------------------------------------------
extern "C" void kernel_launch(void* const* d_in, const int* in_sizes, int n_in,
                              void* d_out, int out_size, void* d_ws, size_t ws_size,
                              hipStream_t stream) {
  const float* x          = (const float*)d_in[0];
  const float* w_qkv      = (const float*)d_in[1];
  const float* b_qkv      = (const float*)d_in[2];
  const float* w_out      = (const float*)d_in[3];
  const float* b_out      = (const float*)d_in[4];
  const float* rope_freqs = (const float*)d_in[5];
  float* out = (float*)d_out;

  char* ws = (char*)d_ws;
  unsigned short* x_bf    = (unsigned short*)(ws + 0);          // 8 MB (aliased by attn_bf)
  unsigned short* attn_bf = x_bf;
  unsigned short* q_bf    = (unsigned short*)(ws + 8388608);
  unsigned short* k_bf    = (unsigned short*)(ws + 16777216);
  unsigned short* v_t     = (unsigned short*)(ws + 33554432);   // [bh][d][l] bf16, 8 MB
  unsigned short* wqkvT   = (unsigned short*)(ws + 41943040);
  unsigned short* woutT   = (unsigned short*)(ws + 48234496);

  hipLaunchKernelGGL(cvt_f32_bf16, dim3(1024), dim3(256), 0, stream, x, x_bf, 1048576);
  hipLaunchKernelGGL(transpose_cvt, dim3(48, 16), dim3(256), 0, stream, w_qkv, wqkvT, 1024, 3072);
  hipLaunchKernelGGL(transpose_cvt, dim3(16, 16), dim3(256), 0, stream, w_out, woutT, 1024, 1024);
  // qkv GEMM + fused bias/RoPE/V-transpose epilogue (768 blocks, XCD-swizzled)
  hipLaunchKernelGGL((mm128b<0, 3>), dim3(768), dim3(256), 0, stream,
                     x_bf, wqkvT, b_qkv, q_bf, k_bf, v_t, (float*)nullptr, rope_freqs);
  // attention (256 blocks, XCD-swizzled)
  hipLaunchKernelGGL(attn_mfma5, dim3(256), dim3(256), 0, stream, q_bf, k_bf, v_t, attn_bf);
  // out projection (256 blocks, XCD-swizzled)
  hipLaunchKernelGGL((mm128b<1, 1>), dim3(256), dim3(256), 0, stream,
                     attn_bf, woutT, b_out,
                     (unsigned short*)nullptr, (unsigned short*)nullptr, (unsigned short*)nullptr,
                     out, (const float*)nullptr);
}